// Round 10
// baseline (3062.875 us; speedup 1.0000x reference)
//
#include <hip/hip_runtime.h>
#include <hip/hip_bf16.h>

namespace {

constexpr int NB = 4;          // batch
constexpr int CI = 2048;       // in channels
constexpr int CO = 1024;       // out channels
constexpr int HW = 4096;       // H*W
constexpr int MTOT = NB * HW;  // 16384 flattened rows

typedef __attribute__((ext_vector_type(8))) short bf16x8;
typedef __attribute__((ext_vector_type(4))) float f32x4;
typedef __hip_bfloat16 bf16;

__device__ __forceinline__ void g2l16(void* lds, const void* g) {
  __builtin_amdgcn_global_load_lds((const __attribute__((address_space(1))) void*)g,
                                   (__attribute__((address_space(3))) void*)lds,
                                   16, 0, 0);
}

__global__ void zero_k(float* __restrict__ p, int n) {
  int i = blockIdx.x * 256 + threadIdx.x;
  if (i < n) p[i] = 0.f;
}

// all six weight casts in one launch; y<3 are CI*CO, y>=3 are CO*CO; float4->ushort4
__global__ void castw6_k(const float* s0, const float* s1, const float* s2,
                         const float* s3, const float* s4, const float* s5,
                         bf16* d0, bf16* d1, bf16* d2, bf16* d3, bf16* d4, bf16* d5) {
  int y = blockIdx.y;
  const float* s = (y == 0) ? s0 : (y == 1) ? s1 : (y == 2) ? s2 : (y == 3) ? s3 : (y == 4) ? s4 : s5;
  bf16* d = (y == 0) ? d0 : (y == 1) ? d1 : (y == 2) ? d2 : (y == 3) ? d3 : (y == 4) ? d4 : d5;
  int n4 = ((y < 3) ? CI * CO : CO * CO) >> 2;
  int i = blockIdx.x * 256 + threadIdx.x;
  if (i < n4) {
    float4 v = ((const float4*)s)[i];
    union { ushort4 u; bf16 h[4]; } pk;
    pk.h[0] = __float2bfloat16(v.x);
    pk.h[1] = __float2bfloat16(v.y);
    pk.h[2] = __float2bfloat16(v.z);
    pk.h[3] = __float2bfloat16(v.w);
    ((ushort4*)d)[i] = pk.u;
  }
}

// dst[b,p4..p4+3] += sum over 128-channel chunk of src[b,c,p]; float4 loads.
// grid (HW/1024, CI/128, NB), block 256
__global__ void nc_sum_k(const float* __restrict__ src, float* __restrict__ dst) {
  int p4 = (blockIdx.x * 256 + threadIdx.x) * 4;
  int c0 = blockIdx.y * 128;
  int b = blockIdx.z;
  const float* s = src + ((long)b * CI + c0) * HW + p4;
  float4 a = make_float4(0.f, 0.f, 0.f, 0.f);
  #pragma unroll 4
  for (int c = 0; c < 128; ++c) {
    float4 v = *(const float4*)(s + (long)c * HW);
    a.x += v.x; a.y += v.y; a.z += v.z; a.w += v.w;
  }
  float* dp = dst + b * HW + p4;
  atomicAdd(dp + 0, a.x);
  atomicAdd(dp + 1, a.y);
  atomicAdd(dp + 2, a.z);
  atomicAdd(dp + 3, a.w);
}

// 64x64-tile float4 transpose: dst[b, s, r] = src[b, r, s]; grid (R/64, S/64, NB)
template <typename TO>
__global__ void transpose64_k(const float* __restrict__ src, TO* __restrict__ dst,
                              int R, int S) {
  __shared__ float tile[64][65];
  const int b = blockIdx.z;
  const int r0 = blockIdx.x * 64, s0 = blockIdx.y * 64;
  const int t = threadIdx.x;
  const int fc = t & 15;        // float4 column
  const int rr = t >> 4;        // 16 rows / pass
  const float* sp = src + ((size_t)b * R + r0) * S + s0;
  #pragma unroll
  for (int i = 0; i < 4; ++i) {
    float4 v = *(const float4*)(sp + (size_t)(rr + i * 16) * S + fc * 4);
    tile[rr + i * 16][fc * 4 + 0] = v.x;
    tile[rr + i * 16][fc * 4 + 1] = v.y;
    tile[rr + i * 16][fc * 4 + 2] = v.z;
    tile[rr + i * 16][fc * 4 + 3] = v.w;
  }
  __syncthreads();
  #pragma unroll
  for (int i = 0; i < 4; ++i) {
    const int sr = rr + i * 16;
    float4 w;
    w.x = tile[fc * 4 + 0][sr];
    w.y = tile[fc * 4 + 1][sr];
    w.z = tile[fc * 4 + 2][sr];
    w.w = tile[fc * 4 + 3][sr];
    if constexpr (sizeof(TO) == 4) {
      *(float4*)((float*)dst + ((size_t)b * S + s0 + sr) * R + r0 + fc * 4) = w;
    } else {
      union { ushort4 u; bf16 h[4]; } pk;
      pk.h[0] = __float2bfloat16(w.x);
      pk.h[1] = __float2bfloat16(w.y);
      pk.h[2] = __float2bfloat16(w.z);
      pk.h[3] = __float2bfloat16(w.w);
      *(ushort4*)((bf16*)dst + ((size_t)b * S + s0 + sr) * R + r0 + fc * 4) = pk.u;
    }
  }
}

// aligned (channels-last, bf16), with inlined 5x5 box denom (boxinv fused).
// One block per (b,p); threads cover c in float4.
__global__ void align_k(const float* __restrict__ pmcl, const float* __restrict__ nc,
                        const int* __restrict__ body, bf16* __restrict__ ah) {
  int bp = blockIdx.x;
  int b = bp >> 12, p = bp & 4095;
  int y = p >> 6, x = p & 63;
  int c = threadIdx.x * 4;
  float4 acc = make_float4(0.f, 0.f, 0.f, 0.f);
  if (body[0]) {
    float s25 = 0.f;
    #pragma unroll
    for (int dy = -2; dy <= 2; ++dy) {
      int yy = y + dy;
      if ((unsigned)yy >= 64u) continue;
      #pragma unroll
      for (int dx = -2; dx <= 2; ++dx) {
        int xx = x + dx;
        if ((unsigned)xx >= 64u) continue;
        int sp = yy * 64 + xx;
        float w = nc[b * HW + sp];
        s25 += w;
        float4 v = *(const float4*)(pmcl + ((long)b * HW + sp) * CO + c);
        acc.x += w * v.x; acc.y += w * v.y; acc.z += w * v.z; acc.w += w * v.w;
      }
    }
    float s = 1.f / (2048.f * s25);
    acc.x *= s; acc.y *= s; acc.z *= s; acc.w *= s;
  } else {
    acc = *(const float4*)(pmcl + (long)bp * CO + c);
  }
  union { ushort4 u; bf16 h[4]; } pk;
  pk.h[0] = __float2bfloat16(acc.x);
  pk.h[1] = __float2bfloat16(acc.y);
  pk.h[2] = __float2bfloat16(acc.z);
  pk.h[3] = __float2bfloat16(acc.w);
  *(ushort4*)(ah + (long)bp * CO + c) = pk.u;
}

// ---------------------------------------------------------------------------
// 256x256-tile dual-K GEMM. BK=32, ring-2 (2 x 32 KiB = 64 KiB LDS -> TWO
// blocks/CU possible), one barrier per phase (R8/R9-proven schedule):
//   [vmcnt(0) (drains own stage tp, issued a phase ago); barrier (all stage-tp
//    writes visible; all reads of buf[(tp+1)&1] from phase tp-1 consumed);
//    STAGE(tp+1) -> other buffer; 12 ds_read_b128; 32 MFMA]
// Swizzled LDS (0 conflicts, both-sides rule), setprio, R5 grid orientation.
// MODE 4 (gridDim.z=2, FUSED zt+ar): blocks (x,y,0) and (x,y,1) co-reside on
//   one CU, stage IDENTICAL A-panels (L2 hits) and decorrelate barrier stalls
//   (m114): iz=0 -> zt = bf16(relu(Wz@curr + Uz@align + b));
//           iz=1 -> ar = bf16(align * relu(Wr@curr + Ur@align + b))
// MODE 2: m = relu(W@curr + U@ar + b); out[b,o,p] = (1-zt)*align + zt*m
//         (f32, chan-FIRST float4 over 4 consecutive p)
// C[p,o] = sum_k A1[p,k]B1[o,k] + sum_k A2[p,k]B2[o,k];  K1=2048, K2=1024.
// ---------------------------------------------------------------------------
template <int MODE>
__global__ __launch_bounds__(512, 4) void gemm256(
    const bf16* __restrict__ A1, const bf16* __restrict__ B1a, const bf16* __restrict__ B1b,
    const bf16* __restrict__ A2, const bf16* __restrict__ B2a, const bf16* __restrict__ B2b,
    const float* __restrict__ b1a, const float* __restrict__ b1b,
    const float* __restrict__ b2a, const float* __restrict__ b2b,
    const bf16* __restrict__ ztp, const bf16* __restrict__ aligh,
    bf16* __restrict__ outa, bf16* __restrict__ outb, float* __restrict__ outcf) {
  constexpr int NT1 = CI / 32;        // 64
  constexpr int NT = NT1 + CO / 32;   // 96
  __shared__ __align__(16) char lds[65536];
  const int iz = (MODE == 4) ? blockIdx.z : 0;
  const bf16* B1 = (MODE == 4 && iz) ? B1b : B1a;
  const bf16* B2 = (MODE == 4 && iz) ? B2b : B2a;
  const float* bias1 = (MODE == 4 && iz) ? b1b : b1a;
  const float* bias2 = (MODE == 4 && iz) ? b2b : b2a;
  const int t = threadIdx.x, lane = t & 63, wid = t >> 6;
  const int wm = wid >> 2, wn = wid & 3;
  const int m0 = blockIdx.x * 256, n0 = blockIdx.y * 256;
  const int fr = lane & 15, kq = lane >> 4;

  // --- staging source precompute (inverse swizzle on global address) ---
  const int b0i = (wid << 7) + lane;
  const int line0 = b0i >> 3;
  const int c3 = (b0i & 7) ^ (line0 & 7);
  const int row0 = 2 * line0 + (c3 >> 2);
  const int k16 = c3 & 3;
  const char* pa1 = (const char*)A1 + (((size_t)(m0 + row0) * CI + k16 * 8) << 1);
  const char* pa1h = pa1 + ((size_t)CI << 5);   // +16 rows
  const char* pb1 = (const char*)B1 + (((size_t)(n0 + row0) * CI + k16 * 8) << 1);
  const char* pb1h = pb1 + ((size_t)CI << 5);
  const char* pa2 = (const char*)A2 + (((size_t)(m0 + row0) * CO + k16 * 8) << 1);
  const char* pa2h = pa2 + ((size_t)CO << 5);
  const char* pb2 = (const char*)B2 + (((size_t)(n0 + row0) * CO + k16 * 8) << 1);
  const char* pb2h = pb2 + ((size_t)CO << 5);

  auto STAGE = [&](int s) {
    const char *sa, *sah, *sb, *sbh;
    if (s < NT1) {
      size_t so = (size_t)s << 6;
      sa = pa1 + so; sah = pa1h + so; sb = pb1 + so; sbh = pb1h + so;
    } else {
      size_t so = (size_t)(s - NT1) << 6;
      sa = pa2 + so; sah = pa2h + so; sb = pb2 + so; sbh = pb2h + so;
    }
    char* d = lds + ((s & 1) << 15) + (wid << 11) + (lane << 4);
    g2l16(d, sa);
    g2l16(d + 1024, sah);
    g2l16(d + 16384, sb);
    g2l16(d + 17408, sbh);
  };

  // --- fragment LDS read offsets (swizzled), loop-invariant ---
  int offA[8], offB[4];
  #pragma unroll
  for (int mi = 0; mi < 8; ++mi) {
    int r = (wm << 7) + (mi << 4) + fr;
    int ln = r >> 1;
    int cc = ((r & 1) << 2) | kq;
    offA[mi] = (ln << 7) + ((cc ^ (ln & 7)) << 4);
  }
  #pragma unroll
  for (int ni = 0; ni < 4; ++ni) {
    int r = (wn << 6) + (ni << 4) + fr;
    int ln = r >> 1;
    int cc = ((r & 1) << 2) | kq;
    offB[ni] = 16384 + (ln << 7) + ((cc ^ (ln & 7)) << 4);
  }

  f32x4 acc[8][4] = {};

  STAGE(0);

  #pragma unroll 1
  for (int tp = 0; tp < NT; ++tp) {
    asm volatile("s_waitcnt vmcnt(0)" ::: "memory");   // own stage-tp loads retired
    __builtin_amdgcn_s_barrier();                      // writes visible; prior reads consumed
    asm volatile("" ::: "memory");
    if (tp + 1 < NT) STAGE(tp + 1);                    // -> other buffer, safe
    const char* buf = lds + ((tp & 1) << 15);
    bf16x8 av[8], bv[4];
    #pragma unroll
    for (int mi = 0; mi < 8; ++mi) av[mi] = *(const bf16x8*)(buf + offA[mi]);
    #pragma unroll
    for (int ni = 0; ni < 4; ++ni) bv[ni] = *(const bf16x8*)(buf + offB[ni]);
    __builtin_amdgcn_s_setprio(1);
    #pragma unroll
    for (int mi = 0; mi < 8; ++mi)
      #pragma unroll
      for (int ni = 0; ni < 4; ++ni)
        acc[mi][ni] = __builtin_amdgcn_mfma_f32_16x16x32_bf16(av[mi], bv[ni], acc[mi][ni], 0, 0, 0);
    __builtin_amdgcn_s_setprio(0);
    asm volatile("" ::: "memory");
  }

  // --- epilogue ---
  #pragma unroll
  for (int mi = 0; mi < 8; ++mi) {
    const int r0 = m0 + (wm << 7) + (mi << 4) + (kq << 2);
    #pragma unroll
    for (int ni = 0; ni < 4; ++ni) {
      const int col = n0 + (wn << 6) + (ni << 4) + fr;
      const float bsum = bias1[col] + bias2[col];
      if (MODE == 2) {
        // channels-first float4 write: 4 consecutive p at fixed (b, col)
        const int bb = r0 >> 12, p0 = r0 & 4095;
        float4 o;
        float* po = &o.x;
        #pragma unroll
        for (int j = 0; j < 4; ++j) {
          const size_t idx = (size_t)(r0 + j) * CO + col;
          float m = fmaxf(acc[mi][ni][j] + bsum, 0.f);
          float z = __bfloat162float(ztp[idx]);
          float a = __bfloat162float(aligh[idx]);
          po[j] = (1.f - z) * a + z * m;
        }
        *(float4*)(outcf + ((size_t)bb * CO + col) * HW + p0) = o;
      } else {  // MODE 4
        #pragma unroll
        for (int j = 0; j < 4; ++j) {
          const size_t idx = (size_t)(r0 + j) * CO + col;
          float v = fmaxf(acc[mi][ni][j] + bsum, 0.f);
          if (iz == 0) {
            outa[idx] = __float2bfloat16(v);
          } else {
            outb[idx] = __float2bfloat16(__bfloat162float(aligh[idx]) * v);
          }
        }
      }
    }
  }
}

}  // namespace

extern "C" void kernel_launch(void* const* d_in, const int* in_sizes, int n_in,
                              void* d_out, int out_size, void* d_ws, size_t ws_size,
                              hipStream_t stream) {
  const float* curr_F = (const float*)d_in[0];
  const float* prev_F = (const float*)d_in[1];
  const float* prev_M = (const float*)d_in[2];
  const float* Wz_w = (const float*)d_in[3];
  const float* Wz_b = (const float*)d_in[4];
  const float* Wr_w = (const float*)d_in[5];
  const float* Wr_b = (const float*)d_in[6];
  const float* W_w  = (const float*)d_in[7];
  const float* W_b  = (const float*)d_in[8];
  const float* Uz_w = (const float*)d_in[9];
  const float* Uz_b = (const float*)d_in[10];
  const float* Ur_w = (const float*)d_in[11];
  const float* Ur_b = (const float*)d_in[12];
  const float* U_w  = (const float*)d_in[13];
  const float* U_b  = (const float*)d_in[14];
  const int* body   = (const int*)d_in[15];
  float* out = (float*)d_out;

  char* ws = (char*)d_ws;
  const size_t M64 = 1ull << 26;  // 64 MiB
  const size_t M32 = 1ull << 25;  // 32 MiB
  // region0: currF bf16 cl (read-only through all GEMMs)
  bf16*  currF_h   = (bf16*)(ws);
  // region1: prevM f32 cl (dead after align_k) -> zt bf16 reuses its space
  float* prevM_cl  = (float*)(ws + M64);
  bf16*  zt        = (bf16*)(ws + M64);
  bf16*  align_h   = (bf16*)(ws + 2 * M64);
  bf16*  ar_h      = (bf16*)(ws + 2 * M64 + M32);
  char*  wb        = ws + 2 * M64 + 2 * M32;
  bf16* Wz_h = (bf16*)wb;
  bf16* Wr_h = Wz_h + (size_t)CO * CI;
  bf16* W_h  = Wr_h + (size_t)CO * CI;
  bf16* Uz_h = W_h  + (size_t)CO * CI;
  bf16* Ur_h = Uz_h + (size_t)CO * CO;
  bf16* U_h  = Ur_h + (size_t)CO * CO;
  float* prev_nc = (float*)(U_h + (size_t)CO * CO);

  // weights -> bf16 (one launch)
  castw6_k<<<dim3((CI * CO) / 1024, 6), 256, 0, stream>>>(
      Wz_w, Wr_w, W_w, Uz_w, Ur_w, U_w, Wz_h, Wr_h, W_h, Uz_h, Ur_h, U_h);

  // prev_nc = sum_c prev_F
  zero_k<<<dim3((NB * HW) / 256), 256, 0, stream>>>(prev_nc, NB * HW);
  nc_sum_k<<<dim3(HW / 1024, CI / 128, NB), 256, 0, stream>>>(prev_F, prev_nc);

  // transposes to channels-last (vectorized 64x64)
  transpose64_k<bf16><<<dim3(CI / 64, HW / 64, NB), 256, 0, stream>>>(curr_F, currF_h, CI, HW);
  transpose64_k<float><<<dim3(CO / 64, HW / 64, NB), 256, 0, stream>>>(prev_M, prevM_cl, CO, HW);

  // aligned (boxinv fused)
  align_k<<<dim3(NB * HW), 256, 0, stream>>>(prevM_cl, prev_nc, body, align_h);

  // FUSED zt+ar dispatch: grid (64,4,2) = 512 blocks -> 2 co-resident
  // blocks/CU sharing A-panels and decorrelating barrier stalls.
  dim3 ggf(MTOT / 256, CO / 256, 2);
  gemm256<4><<<ggf, 512, 0, stream>>>(
      currF_h, Wz_h, Wr_h, align_h, Uz_h, Ur_h,
      Wz_b, Wr_b, Uz_b, Ur_b,
      nullptr, align_h, zt, ar_h, nullptr);

  // out[b,o,p] = (1-zt)*aligned + zt*relu(W@curr + U@ar + W_b + U_b)
  dim3 gg(MTOT / 256, CO / 256);
  gemm256<2><<<gg, 512, 0, stream>>>(
      currF_h, W_h, nullptr, ar_h, U_h, nullptr,
      W_b, nullptr, U_b, nullptr,
      zt, align_h, nullptr, nullptr, out);
}

// Round 11
// 697.909 us; speedup vs baseline: 4.3886x; 4.3886x over previous
//
#include <hip/hip_runtime.h>
#include <hip/hip_bf16.h>

namespace {

constexpr int NB = 4;          // batch
constexpr int CI = 2048;       // in channels
constexpr int CO = 1024;       // out channels
constexpr int HW = 4096;       // H*W
constexpr int MTOT = NB * HW;  // 16384 flattened rows

typedef __attribute__((ext_vector_type(8))) short bf16x8;
typedef __attribute__((ext_vector_type(4))) float f32x4;
typedef __hip_bfloat16 bf16;

__device__ __forceinline__ void g2l16(void* lds, const void* g) {
  __builtin_amdgcn_global_load_lds((const __attribute__((address_space(1))) void*)g,
                                   (__attribute__((address_space(3))) void*)lds,
                                   16, 0, 0);
}

__global__ void zero_k(float* __restrict__ p, int n) {
  int i = blockIdx.x * 256 + threadIdx.x;
  if (i < n) p[i] = 0.f;
}

// all six weight casts in one launch; y<3 are CI*CO, y>=3 are CO*CO; float4->ushort4
__global__ void castw6_k(const float* s0, const float* s1, const float* s2,
                         const float* s3, const float* s4, const float* s5,
                         bf16* d0, bf16* d1, bf16* d2, bf16* d3, bf16* d4, bf16* d5) {
  int y = blockIdx.y;
  const float* s = (y == 0) ? s0 : (y == 1) ? s1 : (y == 2) ? s2 : (y == 3) ? s3 : (y == 4) ? s4 : s5;
  bf16* d = (y == 0) ? d0 : (y == 1) ? d1 : (y == 2) ? d2 : (y == 3) ? d3 : (y == 4) ? d4 : d5;
  int n4 = ((y < 3) ? CI * CO : CO * CO) >> 2;
  int i = blockIdx.x * 256 + threadIdx.x;
  if (i < n4) {
    float4 v = ((const float4*)s)[i];
    union { ushort4 u; bf16 h[4]; } pk;
    pk.h[0] = __float2bfloat16(v.x);
    pk.h[1] = __float2bfloat16(v.y);
    pk.h[2] = __float2bfloat16(v.z);
    pk.h[3] = __float2bfloat16(v.w);
    ((ushort4*)d)[i] = pk.u;
  }
}

// dst[b,p4..p4+3] += sum over 128-channel chunk of src[b,c,p]; float4 loads.
// grid (HW/1024, CI/128, NB), block 256
__global__ void nc_sum_k(const float* __restrict__ src, float* __restrict__ dst) {
  int p4 = (blockIdx.x * 256 + threadIdx.x) * 4;
  int c0 = blockIdx.y * 128;
  int b = blockIdx.z;
  const float* s = src + ((long)b * CI + c0) * HW + p4;
  float4 a = make_float4(0.f, 0.f, 0.f, 0.f);
  #pragma unroll 4
  for (int c = 0; c < 128; ++c) {
    float4 v = *(const float4*)(s + (long)c * HW);
    a.x += v.x; a.y += v.y; a.z += v.z; a.w += v.w;
  }
  float* dp = dst + b * HW + p4;
  atomicAdd(dp + 0, a.x);
  atomicAdd(dp + 1, a.y);
  atomicAdd(dp + 2, a.z);
  atomicAdd(dp + 3, a.w);
}

// 64x64-tile float4 transpose: dst[b, s, r] = src[b, r, s]; grid (R/64, S/64, NB)
template <typename TO>
__global__ void transpose64_k(const float* __restrict__ src, TO* __restrict__ dst,
                              int R, int S) {
  __shared__ float tile[64][65];
  const int b = blockIdx.z;
  const int r0 = blockIdx.x * 64, s0 = blockIdx.y * 64;
  const int t = threadIdx.x;
  const int fc = t & 15;        // float4 column
  const int rr = t >> 4;        // 16 rows / pass
  const float* sp = src + ((size_t)b * R + r0) * S + s0;
  #pragma unroll
  for (int i = 0; i < 4; ++i) {
    float4 v = *(const float4*)(sp + (size_t)(rr + i * 16) * S + fc * 4);
    tile[rr + i * 16][fc * 4 + 0] = v.x;
    tile[rr + i * 16][fc * 4 + 1] = v.y;
    tile[rr + i * 16][fc * 4 + 2] = v.z;
    tile[rr + i * 16][fc * 4 + 3] = v.w;
  }
  __syncthreads();
  #pragma unroll
  for (int i = 0; i < 4; ++i) {
    const int sr = rr + i * 16;
    float4 w;
    w.x = tile[fc * 4 + 0][sr];
    w.y = tile[fc * 4 + 1][sr];
    w.z = tile[fc * 4 + 2][sr];
    w.w = tile[fc * 4 + 3][sr];
    if constexpr (sizeof(TO) == 4) {
      *(float4*)((float*)dst + ((size_t)b * S + s0 + sr) * R + r0 + fc * 4) = w;
    } else {
      union { ushort4 u; bf16 h[4]; } pk;
      pk.h[0] = __float2bfloat16(w.x);
      pk.h[1] = __float2bfloat16(w.y);
      pk.h[2] = __float2bfloat16(w.z);
      pk.h[3] = __float2bfloat16(w.w);
      *(ushort4*)((bf16*)dst + ((size_t)b * S + s0 + sr) * R + r0 + fc * 4) = pk.u;
    }
  }
}

// aligned (channels-last, bf16), with inlined 5x5 box denom (boxinv fused).
// One block per (b,p); threads cover c in float4.
__global__ void align_k(const float* __restrict__ pmcl, const float* __restrict__ nc,
                        const int* __restrict__ body, bf16* __restrict__ ah) {
  int bp = blockIdx.x;
  int b = bp >> 12, p = bp & 4095;
  int y = p >> 6, x = p & 63;
  int c = threadIdx.x * 4;
  float4 acc = make_float4(0.f, 0.f, 0.f, 0.f);
  if (body[0]) {
    float s25 = 0.f;
    #pragma unroll
    for (int dy = -2; dy <= 2; ++dy) {
      int yy = y + dy;
      if ((unsigned)yy >= 64u) continue;
      #pragma unroll
      for (int dx = -2; dx <= 2; ++dx) {
        int xx = x + dx;
        if ((unsigned)xx >= 64u) continue;
        int sp = yy * 64 + xx;
        float w = nc[b * HW + sp];
        s25 += w;
        float4 v = *(const float4*)(pmcl + ((long)b * HW + sp) * CO + c);
        acc.x += w * v.x; acc.y += w * v.y; acc.z += w * v.z; acc.w += w * v.w;
      }
    }
    float s = 1.f / (2048.f * s25);
    acc.x *= s; acc.y *= s; acc.z *= s; acc.w *= s;
  } else {
    acc = *(const float4*)(pmcl + (long)bp * CO + c);
  }
  union { ushort4 u; bf16 h[4]; } pk;
  pk.h[0] = __float2bfloat16(acc.x);
  pk.h[1] = __float2bfloat16(acc.y);
  pk.h[2] = __float2bfloat16(acc.z);
  pk.h[3] = __float2bfloat16(acc.w);
  *(ushort4*)(ah + (long)bp * CO + c) = pk.u;
}

// ---------------------------------------------------------------------------
// 256x256-tile dual-K GEMM, B-BYPASS variant: only A is staged through LDS
// (BK=64, ring-2 of 32 KiB -> 64 KiB total); B fragments load straight from
// global to VGPR (per-wave: 16 rows x 64 contiguous bytes -> coalesced,
// L2-resident panels; same L2 traffic as the old g2l path, FETCH unchanged).
// This removes 32 KiB of ds_reads + 32 KiB of LDS writes from each CU-phase,
// the serialized term the R2..R9 schedule experiments could not reduce.
// One barrier per phase (R9-proven): [vmcnt(0); barrier; STAGE(tp+1)->other
// buffer; per k-half: 4 B global loads + 8 A ds_reads + 32 MFMA].
// Swizzled A LDS (0 conflicts, both-sides rule), setprio, R5 grid orientation.
// C[p,o] = sum_k A1[p,k]B1[o,k] + sum_k A2[p,k]B2[o,k];  K1=2048, K2=1024.
// MODE 0: zt[p,o]   = bf16(relu(acc + b1 + b2))              (bf16, chan-last)
// MODE 3: ar[p,o]   = bf16(aligh * relu(acc + b1 + b2))      (bf16, chan-last)
// MODE 2: m = relu(acc + b1 + b2);
//         out[b,o,p] = (1-zt)*aligh + zt*m                   (f32, chan-FIRST)
// ---------------------------------------------------------------------------
template <int MODE>
__global__ __launch_bounds__(512, 2) void gemm256(
    const bf16* __restrict__ A1, const bf16* __restrict__ B1,
    const bf16* __restrict__ A2, const bf16* __restrict__ B2,
    const float* __restrict__ bias1, const float* __restrict__ bias2,
    const bf16* __restrict__ ztp, const bf16* __restrict__ aligh,
    bf16* __restrict__ outh, float* __restrict__ outcf) {
  constexpr int NT1 = CI / 64;        // 32
  constexpr int NT = NT1 + CO / 64;   // 48
  __shared__ __align__(16) char lds[65536];
  const int t = threadIdx.x, lane = t & 63, wid = t >> 6;
  const int wm = wid >> 2, wn = wid & 3;
  const int m0 = blockIdx.x * 256, n0 = blockIdx.y * 256;
  const int fr = lane & 15, kq = lane >> 4;

  // --- A staging source precompute (inverse swizzle on global address) ---
  const int b0i = (wid << 7) + lane;
  const int line0 = b0i >> 3;
  const int c3 = (b0i & 7) ^ (line0 & 7);
  const int row0 = 2 * line0 + (c3 >> 2);
  const int k16 = c3 & 3;
  const char* pa1 = (const char*)A1 + (((size_t)(m0 + row0) * CI + k16 * 8) << 1);
  const char* pa1h = pa1 + ((size_t)CI << 5);   // +16 rows
  const char* pa2 = (const char*)A2 + (((size_t)(m0 + row0) * CO + k16 * 8) << 1);
  const char* pa2h = pa2 + ((size_t)CO << 5);

  // --- B fragment lane bases (global, coalesced 64B/row) ---
  const bf16* qb1 = B1 + (size_t)(n0 + wn * 64 + fr) * CI + kq * 8;
  const bf16* qb2 = B2 + (size_t)(n0 + wn * 64 + fr) * CO + kq * 8;

  // STAGE(s): one BK=64 A tile = two kh-halves (4 g2l16 / thread, 32 KiB).
  auto STAGE = [&](int s) {
    const char *sa, *sah;
    if (s < NT1) {
      size_t so = (size_t)s << 7;                // 64 elems = 128 B per tile
      sa = pa1 + so; sah = pa1h + so;
    } else {
      size_t so = (size_t)(s - NT1) << 7;
      sa = pa2 + so; sah = pa2h + so;
    }
    char* d = lds + ((s & 1) << 15) + (wid << 11) + (lane << 4);
    g2l16(d, sa);                 // kh0
    g2l16(d + 1024, sah);
    g2l16(d + 16384, sa + 64);    // kh1 (next 32 k's)
    g2l16(d + 17408, sah + 64);
  };

  // --- A fragment LDS read offsets (swizzled, kh0; kh1 adds 16384) ---
  int offA[8];
  #pragma unroll
  for (int mi = 0; mi < 8; ++mi) {
    int r = (wm << 7) + (mi << 4) + fr;
    int ln = r >> 1;
    int cc = ((r & 1) << 2) | kq;
    offA[mi] = (ln << 7) + ((cc ^ (ln & 7)) << 4);
  }

  f32x4 acc[8][4] = {};

  STAGE(0);

  #pragma unroll 1
  for (int tp = 0; tp < NT; ++tp) {
    asm volatile("s_waitcnt vmcnt(0)" ::: "memory");   // stage tp retired (~free)
    __builtin_amdgcn_s_barrier();                      // writes visible; prior reads consumed
    asm volatile("" ::: "memory");
    if (tp + 1 < NT) STAGE(tp + 1);                    // -> other buffer, safe
    const char* buf = lds + ((tp & 1) << 15);
    const bf16* qb;
    size_t ldb, ko;
    if (tp < NT1) { qb = qb1; ldb = CI; ko = (size_t)tp * 64; }
    else          { qb = qb2; ldb = CO; ko = (size_t)(tp - NT1) * 64; }
    bf16x8 av[8], bv[4];
    // k0 half: B from global (L2), A from LDS
    #pragma unroll
    for (int ni = 0; ni < 4; ++ni) bv[ni] = *(const bf16x8*)(qb + (size_t)ni * 16 * ldb + ko);
    #pragma unroll
    for (int mi = 0; mi < 8; ++mi) av[mi] = *(const bf16x8*)(buf + offA[mi]);
    __builtin_amdgcn_s_setprio(1);
    #pragma unroll
    for (int mi = 0; mi < 8; ++mi)
      #pragma unroll
      for (int ni = 0; ni < 4; ++ni)
        acc[mi][ni] = __builtin_amdgcn_mfma_f32_16x16x32_bf16(av[mi], bv[ni], acc[mi][ni], 0, 0, 0);
    __builtin_amdgcn_s_setprio(0);
    // k1 half
    #pragma unroll
    for (int ni = 0; ni < 4; ++ni) bv[ni] = *(const bf16x8*)(qb + (size_t)ni * 16 * ldb + ko + 32);
    #pragma unroll
    for (int mi = 0; mi < 8; ++mi) av[mi] = *(const bf16x8*)(buf + 16384 + offA[mi]);
    __builtin_amdgcn_s_setprio(1);
    #pragma unroll
    for (int mi = 0; mi < 8; ++mi)
      #pragma unroll
      for (int ni = 0; ni < 4; ++ni)
        acc[mi][ni] = __builtin_amdgcn_mfma_f32_16x16x32_bf16(av[mi], bv[ni], acc[mi][ni], 0, 0, 0);
    __builtin_amdgcn_s_setprio(0);
    asm volatile("" ::: "memory");
  }

  // --- epilogue ---
  #pragma unroll
  for (int mi = 0; mi < 8; ++mi) {
    const int r0 = m0 + (wm << 7) + (mi << 4) + (kq << 2);
    #pragma unroll
    for (int ni = 0; ni < 4; ++ni) {
      const int col = n0 + (wn << 6) + (ni << 4) + fr;
      const float bsum = bias1[col] + bias2[col];
      if (MODE == 2) {
        // channels-first float4 write: 4 consecutive p at fixed (b, col)
        const int bb = r0 >> 12, p0 = r0 & 4095;
        float4 o;
        float* po = &o.x;
        #pragma unroll
        for (int j = 0; j < 4; ++j) {
          const size_t idx = (size_t)(r0 + j) * CO + col;
          float m = fmaxf(acc[mi][ni][j] + bsum, 0.f);
          float z = __bfloat162float(ztp[idx]);
          float a = __bfloat162float(aligh[idx]);
          po[j] = (1.f - z) * a + z * m;
        }
        *(float4*)(outcf + ((size_t)bb * CO + col) * HW + p0) = o;
      } else {
        #pragma unroll
        for (int j = 0; j < 4; ++j) {
          const size_t idx = (size_t)(r0 + j) * CO + col;
          float v = fmaxf(acc[mi][ni][j] + bsum, 0.f);
          if (MODE == 0) {
            outh[idx] = __float2bfloat16(v);
          } else {  // MODE 3
            outh[idx] = __float2bfloat16(__bfloat162float(aligh[idx]) * v);
          }
        }
      }
    }
  }
}

}  // namespace

extern "C" void kernel_launch(void* const* d_in, const int* in_sizes, int n_in,
                              void* d_out, int out_size, void* d_ws, size_t ws_size,
                              hipStream_t stream) {
  const float* curr_F = (const float*)d_in[0];
  const float* prev_F = (const float*)d_in[1];
  const float* prev_M = (const float*)d_in[2];
  const float* Wz_w = (const float*)d_in[3];
  const float* Wz_b = (const float*)d_in[4];
  const float* Wr_w = (const float*)d_in[5];
  const float* Wr_b = (const float*)d_in[6];
  const float* W_w  = (const float*)d_in[7];
  const float* W_b  = (const float*)d_in[8];
  const float* Uz_w = (const float*)d_in[9];
  const float* Uz_b = (const float*)d_in[10];
  const float* Ur_w = (const float*)d_in[11];
  const float* Ur_b = (const float*)d_in[12];
  const float* U_w  = (const float*)d_in[13];
  const float* U_b  = (const float*)d_in[14];
  const int* body   = (const int*)d_in[15];
  float* out = (float*)d_out;

  char* ws = (char*)d_ws;
  const size_t M64 = 1ull << 26;  // 64 MiB
  const size_t M32 = 1ull << 25;  // 32 MiB
  // region0: currF bf16 cl (read-only through all GEMMs)
  bf16*  currF_h   = (bf16*)(ws);
  // region1: prevM f32 cl (dead after align_k) -> zt bf16 reuses its space
  float* prevM_cl  = (float*)(ws + M64);
  bf16*  zt        = (bf16*)(ws + M64);
  bf16*  align_h   = (bf16*)(ws + 2 * M64);
  bf16*  ar_h      = (bf16*)(ws + 2 * M64 + M32);
  char*  wb        = ws + 2 * M64 + 2 * M32;
  bf16* Wz_h = (bf16*)wb;
  bf16* Wr_h = Wz_h + (size_t)CO * CI;
  bf16* W_h  = Wr_h + (size_t)CO * CI;
  bf16* Uz_h = W_h  + (size_t)CO * CI;
  bf16* Ur_h = Uz_h + (size_t)CO * CO;
  bf16* U_h  = Ur_h + (size_t)CO * CO;
  float* prev_nc = (float*)(U_h + (size_t)CO * CO);

  // weights -> bf16 (one launch)
  castw6_k<<<dim3((CI * CO) / 1024, 6), 256, 0, stream>>>(
      Wz_w, Wr_w, W_w, Uz_w, Ur_w, U_w, Wz_h, Wr_h, W_h, Uz_h, Ur_h, U_h);

  // prev_nc = sum_c prev_F
  zero_k<<<dim3((NB * HW) / 256), 256, 0, stream>>>(prev_nc, NB * HW);
  nc_sum_k<<<dim3(HW / 1024, CI / 128, NB), 256, 0, stream>>>(prev_F, prev_nc);

  // transposes to channels-last (vectorized 64x64)
  transpose64_k<bf16><<<dim3(CI / 64, HW / 64, NB), 256, 0, stream>>>(curr_F, currF_h, CI, HW);
  transpose64_k<float><<<dim3(CO / 64, HW / 64, NB), 256, 0, stream>>>(prev_M, prevM_cl, CO, HW);

  // aligned (boxinv fused)
  align_k<<<dim3(NB * HW), 256, 0, stream>>>(prevM_cl, prev_nc, body, align_h);

  dim3 gg(MTOT / 256, CO / 256);  // (64, 4): 8 row-panels x 4 col-panels / XCD
  // zt = bf16(relu(Wz@curr + Uz@aligned + biases))   [bn_star is a no-op for B=4]
  gemm256<0><<<gg, 512, 0, stream>>>(currF_h, Wz_h, align_h, Uz_h,
                                     Wz_b, Uz_b, nullptr, nullptr, zt, nullptr);
  // ar = bf16(aligned * relu(Wr@curr + Ur@aligned + biases))
  gemm256<3><<<gg, 512, 0, stream>>>(currF_h, Wr_h, align_h, Ur_h,
                                     Wr_b, Ur_b, nullptr, align_h, ar_h, nullptr);
  // out[b,o,p] = (1-zt)*aligned + zt*relu(W@curr + U@ar + W_b + U_b)
  gemm256<2><<<gg, 512, 0, stream>>>(currF_h, W_h, ar_h, U_h,
                                     W_b, U_b, zt, align_h, nullptr, out);
}

// Round 12
// 509.450 us; speedup vs baseline: 6.0121x; 1.3699x over previous
//
#include <hip/hip_runtime.h>
#include <hip/hip_bf16.h>

namespace {

constexpr int NB = 4;          // batch
constexpr int CI = 2048;       // in channels
constexpr int CO = 1024;       // out channels
constexpr int HW = 4096;       // H*W
constexpr int MTOT = NB * HW;  // 16384 flattened rows

typedef __attribute__((ext_vector_type(8))) short bf16x8;
typedef __attribute__((ext_vector_type(4))) float f32x4;
typedef __hip_bfloat16 bf16;

__device__ __forceinline__ void g2l16(void* lds, const void* g) {
  __builtin_amdgcn_global_load_lds((const __attribute__((address_space(1))) void*)g,
                                   (__attribute__((address_space(3))) void*)lds,
                                   16, 0, 0);
}

__global__ void zero_k(float* __restrict__ p, int n) {
  int i = blockIdx.x * 256 + threadIdx.x;
  if (i < n) p[i] = 0.f;
}

// all six weight casts in one launch; y<3 are CI*CO, y>=3 are CO*CO; float4->ushort4
__global__ void castw6_k(const float* s0, const float* s1, const float* s2,
                         const float* s3, const float* s4, const float* s5,
                         bf16* d0, bf16* d1, bf16* d2, bf16* d3, bf16* d4, bf16* d5) {
  int y = blockIdx.y;
  const float* s = (y == 0) ? s0 : (y == 1) ? s1 : (y == 2) ? s2 : (y == 3) ? s3 : (y == 4) ? s4 : s5;
  bf16* d = (y == 0) ? d0 : (y == 1) ? d1 : (y == 2) ? d2 : (y == 3) ? d3 : (y == 4) ? d4 : d5;
  int n4 = ((y < 3) ? CI * CO : CO * CO) >> 2;
  int i = blockIdx.x * 256 + threadIdx.x;
  if (i < n4) {
    float4 v = ((const float4*)s)[i];
    union { ushort4 u; bf16 h[4]; } pk;
    pk.h[0] = __float2bfloat16(v.x);
    pk.h[1] = __float2bfloat16(v.y);
    pk.h[2] = __float2bfloat16(v.z);
    pk.h[3] = __float2bfloat16(v.w);
    ((ushort4*)d)[i] = pk.u;
  }
}

// dst[b,p4..p4+3] += sum over 128-channel chunk of src[b,c,p]; float4 loads.
// grid (HW/1024, CI/128, NB), block 256
__global__ void nc_sum_k(const float* __restrict__ src, float* __restrict__ dst) {
  int p4 = (blockIdx.x * 256 + threadIdx.x) * 4;
  int c0 = blockIdx.y * 128;
  int b = blockIdx.z;
  const float* s = src + ((long)b * CI + c0) * HW + p4;
  float4 a = make_float4(0.f, 0.f, 0.f, 0.f);
  #pragma unroll 4
  for (int c = 0; c < 128; ++c) {
    float4 v = *(const float4*)(s + (long)c * HW);
    a.x += v.x; a.y += v.y; a.z += v.z; a.w += v.w;
  }
  float* dp = dst + b * HW + p4;
  atomicAdd(dp + 0, a.x);
  atomicAdd(dp + 1, a.y);
  atomicAdd(dp + 2, a.z);
  atomicAdd(dp + 3, a.w);
}

// 64x64-tile float4 transpose: dst[b, s, r] = src[b, r, s]; grid (R/64, S/64, NB)
template <typename TO>
__global__ void transpose64_k(const float* __restrict__ src, TO* __restrict__ dst,
                              int R, int S) {
  __shared__ float tile[64][65];
  const int b = blockIdx.z;
  const int r0 = blockIdx.x * 64, s0 = blockIdx.y * 64;
  const int t = threadIdx.x;
  const int fc = t & 15;        // float4 column
  const int rr = t >> 4;        // 16 rows / pass
  const float* sp = src + ((size_t)b * R + r0) * S + s0;
  #pragma unroll
  for (int i = 0; i < 4; ++i) {
    float4 v = *(const float4*)(sp + (size_t)(rr + i * 16) * S + fc * 4);
    tile[rr + i * 16][fc * 4 + 0] = v.x;
    tile[rr + i * 16][fc * 4 + 1] = v.y;
    tile[rr + i * 16][fc * 4 + 2] = v.z;
    tile[rr + i * 16][fc * 4 + 3] = v.w;
  }
  __syncthreads();
  #pragma unroll
  for (int i = 0; i < 4; ++i) {
    const int sr = rr + i * 16;
    float4 w;
    w.x = tile[fc * 4 + 0][sr];
    w.y = tile[fc * 4 + 1][sr];
    w.z = tile[fc * 4 + 2][sr];
    w.w = tile[fc * 4 + 3][sr];
    if constexpr (sizeof(TO) == 4) {
      *(float4*)((float*)dst + ((size_t)b * S + s0 + sr) * R + r0 + fc * 4) = w;
    } else {
      union { ushort4 u; bf16 h[4]; } pk;
      pk.h[0] = __float2bfloat16(w.x);
      pk.h[1] = __float2bfloat16(w.y);
      pk.h[2] = __float2bfloat16(w.z);
      pk.h[3] = __float2bfloat16(w.w);
      *(ushort4*)((bf16*)dst + ((size_t)b * S + s0 + sr) * R + r0 + fc * 4) = pk.u;
    }
  }
}

// aligned (channels-last, bf16), with inlined 5x5 box denom (boxinv fused).
// One block per (b,p); threads cover c in float4.
__global__ void align_k(const float* __restrict__ pmcl, const float* __restrict__ nc,
                        const int* __restrict__ body, bf16* __restrict__ ah) {
  int bp = blockIdx.x;
  int b = bp >> 12, p = bp & 4095;
  int y = p >> 6, x = p & 63;
  int c = threadIdx.x * 4;
  float4 acc = make_float4(0.f, 0.f, 0.f, 0.f);
  if (body[0]) {
    float s25 = 0.f;
    #pragma unroll
    for (int dy = -2; dy <= 2; ++dy) {
      int yy = y + dy;
      if ((unsigned)yy >= 64u) continue;
      #pragma unroll
      for (int dx = -2; dx <= 2; ++dx) {
        int xx = x + dx;
        if ((unsigned)xx >= 64u) continue;
        int sp = yy * 64 + xx;
        float w = nc[b * HW + sp];
        s25 += w;
        float4 v = *(const float4*)(pmcl + ((long)b * HW + sp) * CO + c);
        acc.x += w * v.x; acc.y += w * v.y; acc.z += w * v.z; acc.w += w * v.w;
      }
    }
    float s = 1.f / (2048.f * s25);
    acc.x *= s; acc.y *= s; acc.z *= s; acc.w *= s;
  } else {
    acc = *(const float4*)(pmcl + (long)bp * CO + c);
  }
  union { ushort4 u; bf16 h[4]; } pk;
  pk.h[0] = __float2bfloat16(acc.x);
  pk.h[1] = __float2bfloat16(acc.y);
  pk.h[2] = __float2bfloat16(acc.z);
  pk.h[3] = __float2bfloat16(acc.w);
  *(ushort4*)(ah + (long)bp * CO + c) = pk.u;
}

// ---------------------------------------------------------------------------
// 256x256-tile dual-K GEMM — R8 configuration (best measured: 123.0 us,
// MfmaUtil 34.7, 0 bank conflicts): BK=32, ring-4 of 32 KiB subtiles,
// prefetch depth 2, ONE barrier per phase, counted vmcnt(8), swizzled LDS
// (both-sides rule), setprio, (64,4) grid orientation.
// Phase tp: [STAGE(tp+2) -> buf[(tp+2)&3] (safe: its reads finished before
// barrier(tp-1)); vmcnt(8) retires stage tp; barrier; 12 ds_read_b128;
// 32 MFMA]. Single barrier/phase lets waves slip (m114 decorrelation).
// C[p,o] = sum_k A1[p,k]B1[o,k] + sum_k A2[p,k]B2[o,k];  K1=2048, K2=1024.
// MODE 0: zt[p,o]   = bf16(relu(acc + b1 + b2))              (bf16, chan-last)
// MODE 3: ar[p,o]   = bf16(aligh * relu(acc + b1 + b2))      (bf16, chan-last)
// MODE 2: m = relu(acc + b1 + b2);
//         out[b,o,p] = (1-zt)*aligh + zt*m                   (f32, chan-FIRST)
// ---------------------------------------------------------------------------
template <int MODE>
__global__ __launch_bounds__(512, 2) void gemm256(
    const bf16* __restrict__ A1, const bf16* __restrict__ B1,
    const bf16* __restrict__ A2, const bf16* __restrict__ B2,
    const float* __restrict__ bias1, const float* __restrict__ bias2,
    const bf16* __restrict__ ztp, const bf16* __restrict__ aligh,
    bf16* __restrict__ outh, float* __restrict__ outcf) {
  constexpr int NT1 = CI / 32;        // 64
  constexpr int NT = NT1 + CO / 32;   // 96
  __shared__ __align__(16) char lds[131072];
  const int t = threadIdx.x, lane = t & 63, wid = t >> 6;
  const int wm = wid >> 2, wn = wid & 3;
  const int m0 = blockIdx.x * 256, n0 = blockIdx.y * 256;
  const int fr = lane & 15, kq = lane >> 4;

  // --- staging source precompute (inverse swizzle on global address) ---
  const int b0i = (wid << 7) + lane;
  const int line0 = b0i >> 3;
  const int c3 = (b0i & 7) ^ (line0 & 7);
  const int row0 = 2 * line0 + (c3 >> 2);
  const int k16 = c3 & 3;
  const char* pa1 = (const char*)A1 + (((size_t)(m0 + row0) * CI + k16 * 8) << 1);
  const char* pa1h = pa1 + ((size_t)CI << 5);   // +16 rows
  const char* pb1 = (const char*)B1 + (((size_t)(n0 + row0) * CI + k16 * 8) << 1);
  const char* pb1h = pb1 + ((size_t)CI << 5);
  const char* pa2 = (const char*)A2 + (((size_t)(m0 + row0) * CO + k16 * 8) << 1);
  const char* pa2h = pa2 + ((size_t)CO << 5);
  const char* pb2 = (const char*)B2 + (((size_t)(n0 + row0) * CO + k16 * 8) << 1);
  const char* pb2h = pb2 + ((size_t)CO << 5);

  auto STAGE = [&](int s) {
    const char *sa, *sah, *sb, *sbh;
    if (s < NT1) {
      size_t so = (size_t)s << 6;
      sa = pa1 + so; sah = pa1h + so; sb = pb1 + so; sbh = pb1h + so;
    } else {
      size_t so = (size_t)(s - NT1) << 6;
      sa = pa2 + so; sah = pa2h + so; sb = pb2 + so; sbh = pb2h + so;
    }
    char* d = lds + ((s & 3) << 15) + (wid << 11) + (lane << 4);
    g2l16(d, sa);
    g2l16(d + 1024, sah);
    g2l16(d + 16384, sb);
    g2l16(d + 17408, sbh);
  };

  // --- fragment LDS read offsets (swizzled), loop-invariant ---
  int offA[8], offB[4];
  #pragma unroll
  for (int mi = 0; mi < 8; ++mi) {
    int r = (wm << 7) + (mi << 4) + fr;
    int ln = r >> 1;
    int cc = ((r & 1) << 2) | kq;
    offA[mi] = (ln << 7) + ((cc ^ (ln & 7)) << 4);
  }
  #pragma unroll
  for (int ni = 0; ni < 4; ++ni) {
    int r = (wn << 6) + (ni << 4) + fr;
    int ln = r >> 1;
    int cc = ((r & 1) << 2) | kq;
    offB[ni] = 16384 + (ln << 7) + ((cc ^ (ln & 7)) << 4);
  }

  f32x4 acc[8][4] = {};

  STAGE(0); STAGE(1);

  #pragma unroll 1
  for (int tp = 0; tp < NT; ++tp) {
    if (tp + 2 < NT) {
      STAGE(tp + 2);                                       // -> buf[(tp+2)&3], safe
      asm volatile("s_waitcnt vmcnt(8)" ::: "memory");     // retire stage tp
    } else if (tp + 1 < NT) {
      asm volatile("s_waitcnt vmcnt(4)" ::: "memory");
    } else {
      asm volatile("s_waitcnt vmcnt(0)" ::: "memory");
    }
    __builtin_amdgcn_s_barrier();                          // all waves' tp loads visible
    asm volatile("" ::: "memory");
    const char* buf = lds + ((tp & 3) << 15);
    bf16x8 av[8], bv[4];
    #pragma unroll
    for (int mi = 0; mi < 8; ++mi) av[mi] = *(const bf16x8*)(buf + offA[mi]);
    #pragma unroll
    for (int ni = 0; ni < 4; ++ni) bv[ni] = *(const bf16x8*)(buf + offB[ni]);
    __builtin_amdgcn_s_setprio(1);
    #pragma unroll
    for (int mi = 0; mi < 8; ++mi)
      #pragma unroll
      for (int ni = 0; ni < 4; ++ni)
        acc[mi][ni] = __builtin_amdgcn_mfma_f32_16x16x32_bf16(av[mi], bv[ni], acc[mi][ni], 0, 0, 0);
    __builtin_amdgcn_s_setprio(0);
    asm volatile("" ::: "memory");
  }

  // --- epilogue ---
  #pragma unroll
  for (int mi = 0; mi < 8; ++mi) {
    const int r0 = m0 + (wm << 7) + (mi << 4) + (kq << 2);
    #pragma unroll
    for (int ni = 0; ni < 4; ++ni) {
      const int col = n0 + (wn << 6) + (ni << 4) + fr;
      const float bsum = bias1[col] + bias2[col];
      if (MODE == 2) {
        // channels-first float4 write: 4 consecutive p at fixed (b, col)
        const int bb = r0 >> 12, p0 = r0 & 4095;
        float4 o;
        float* po = &o.x;
        #pragma unroll
        for (int j = 0; j < 4; ++j) {
          const size_t idx = (size_t)(r0 + j) * CO + col;
          float m = fmaxf(acc[mi][ni][j] + bsum, 0.f);
          float z = __bfloat162float(ztp[idx]);
          float a = __bfloat162float(aligh[idx]);
          po[j] = (1.f - z) * a + z * m;
        }
        *(float4*)(outcf + ((size_t)bb * CO + col) * HW + p0) = o;
      } else {
        #pragma unroll
        for (int j = 0; j < 4; ++j) {
          const size_t idx = (size_t)(r0 + j) * CO + col;
          float v = fmaxf(acc[mi][ni][j] + bsum, 0.f);
          if (MODE == 0) {
            outh[idx] = __float2bfloat16(v);
          } else {  // MODE 3
            outh[idx] = __float2bfloat16(__bfloat162float(aligh[idx]) * v);
          }
        }
      }
    }
  }
}

}  // namespace

extern "C" void kernel_launch(void* const* d_in, const int* in_sizes, int n_in,
                              void* d_out, int out_size, void* d_ws, size_t ws_size,
                              hipStream_t stream) {
  const float* curr_F = (const float*)d_in[0];
  const float* prev_F = (const float*)d_in[1];
  const float* prev_M = (const float*)d_in[2];
  const float* Wz_w = (const float*)d_in[3];
  const float* Wz_b = (const float*)d_in[4];
  const float* Wr_w = (const float*)d_in[5];
  const float* Wr_b = (const float*)d_in[6];
  const float* W_w  = (const float*)d_in[7];
  const float* W_b  = (const float*)d_in[8];
  const float* Uz_w = (const float*)d_in[9];
  const float* Uz_b = (const float*)d_in[10];
  const float* Ur_w = (const float*)d_in[11];
  const float* Ur_b = (const float*)d_in[12];
  const float* U_w  = (const float*)d_in[13];
  const float* U_b  = (const float*)d_in[14];
  const int* body   = (const int*)d_in[15];
  float* out = (float*)d_out;

  char* ws = (char*)d_ws;
  const size_t M64 = 1ull << 26;  // 64 MiB
  const size_t M32 = 1ull << 25;  // 32 MiB
  // region0: currF bf16 cl (read-only through all GEMMs)
  bf16*  currF_h   = (bf16*)(ws);
  // region1: prevM f32 cl (dead after align_k) -> zt bf16 reuses its space
  float* prevM_cl  = (float*)(ws + M64);
  bf16*  zt        = (bf16*)(ws + M64);
  bf16*  align_h   = (bf16*)(ws + 2 * M64);
  bf16*  ar_h      = (bf16*)(ws + 2 * M64 + M32);
  char*  wb        = ws + 2 * M64 + 2 * M32;
  bf16* Wz_h = (bf16*)wb;
  bf16* Wr_h = Wz_h + (size_t)CO * CI;
  bf16* W_h  = Wr_h + (size_t)CO * CI;
  bf16* Uz_h = W_h  + (size_t)CO * CI;
  bf16* Ur_h = Uz_h + (size_t)CO * CO;
  bf16* U_h  = Ur_h + (size_t)CO * CO;
  float* prev_nc = (float*)(U_h + (size_t)CO * CO);

  // weights -> bf16 (one launch)
  castw6_k<<<dim3((CI * CO) / 1024, 6), 256, 0, stream>>>(
      Wz_w, Wr_w, W_w, Uz_w, Ur_w, U_w, Wz_h, Wr_h, W_h, Uz_h, Ur_h, U_h);

  // prev_nc = sum_c prev_F
  zero_k<<<dim3((NB * HW) / 256), 256, 0, stream>>>(prev_nc, NB * HW);
  nc_sum_k<<<dim3(HW / 1024, CI / 128, NB), 256, 0, stream>>>(prev_F, prev_nc);

  // transposes to channels-last (vectorized 64x64)
  transpose64_k<bf16><<<dim3(CI / 64, HW / 64, NB), 256, 0, stream>>>(curr_F, currF_h, CI, HW);
  transpose64_k<float><<<dim3(CO / 64, HW / 64, NB), 256, 0, stream>>>(prev_M, prevM_cl, CO, HW);

  // aligned (boxinv fused)
  align_k<<<dim3(NB * HW), 256, 0, stream>>>(prevM_cl, prev_nc, body, align_h);

  dim3 gg(MTOT / 256, CO / 256);  // (64, 4): 8 row-panels x 4 col-panels / XCD
  // zt = bf16(relu(Wz@curr + Uz@aligned + biases))   [bn_star is a no-op for B=4]
  gemm256<0><<<gg, 512, 0, stream>>>(currF_h, Wz_h, align_h, Uz_h,
                                     Wz_b, Uz_b, nullptr, nullptr, zt, nullptr);
  // ar = bf16(aligned * relu(Wr@curr + Ur@aligned + biases))
  gemm256<3><<<gg, 512, 0, stream>>>(currF_h, Wr_h, align_h, Ur_h,
                                     Wr_b, Ur_b, nullptr, align_h, ar_h, nullptr);
  // out[b,o,p] = (1-zt)*aligned + zt*relu(W@curr + U@ar + W_b + U_b)
  gemm256<2><<<gg, 512, 0, stream>>>(currF_h, W_h, ar_h, U_h,
                                     W_b, U_b, zt, align_h, nullptr, out);
}